// Round 7
// baseline (129.605 us; speedup 1.0000x reference)
//
#include <hip/hip_runtime.h>
#include <stdint.h>

namespace {

typedef short bf16x8 __attribute__((ext_vector_type(8)));
typedef float f32x4 __attribute__((ext_vector_type(4)));
typedef unsigned short u16x4 __attribute__((ext_vector_type(4)));

constexpr int BATCH = 16;
constexpr int LQ = 2048;
constexpr int LK = 2048;
constexpr int DIM = 64;
constexpr int QB = 64;      // q rows per block (4 row-groups x 16)
constexpr int BLOCK = 512;  // 8 waves: w&3 = row-group, w>>2 = k-half
constexpr int NT = 16;      // k-tiles per half (2048 / 2 / 64)
constexpr float SCALE = 0.125f;  // 1/sqrt(64)

// LDS arena halfword offsets
constexpr int O_KHI = 0;      // [2][64*64]
constexpr int O_KLO = 8192;   // [2][64*64]
constexpr int O_VT = 16384;   // [2][64*64]
constexpr int O_PL = 24576;   // [8][16*64]
constexpr int O_MN = 32768;   // [2][64*4]
constexpr int ARENA = 33280;  // 66560 B -> 2 blocks/CU

// d_ws byte offsets for pre-converted operands (flag at 0)
constexpr size_t WS_KHI = 1ull << 20;   // 4 MB  bf16 K-hi, swizzled
constexpr size_t WS_KLO = 6ull << 20;   // 4 MB  bf16 K-lo, swizzled
constexpr size_t WS_VT = 11ull << 20;   // 4 MB  bf16 V^T per-tile, swizzled

// Raw barrier: orders LDS, leaves VMEM in flight (counted separately).
__device__ inline void bar_lds() {
  asm volatile("s_waitcnt lgkmcnt(0)\n\ts_barrier" ::: "memory");
}

__device__ inline void gl_lds16(const unsigned short* g, unsigned short* l) {
  __builtin_amdgcn_global_load_lds(
      (const __attribute__((address_space(1))) unsigned int*)g,
      (__attribute__((address_space(3))) unsigned int*)l, 16, 0, 0);
}

__global__ void detect_mask_dtype(const uint32_t* __restrict__ mask,
                                  int* __restrict__ flag) {
  __shared__ int bad;
  if (threadIdx.x == 0) bad = 0;
  __syncthreads();
  int my = 0;
  for (int i = threadIdx.x; i < 4096; i += 256) {
    uint32_t w = mask[i];
    if (w > 1u && w != 0x3F800000u) my = 1;
  }
  if (my) atomicOr(&bad, 1);
  __syncthreads();
  if (threadIdx.x == 0) *flag = bad;  // 1 -> uint8-packed
}

__device__ inline unsigned short f2bf(float x) {  // RNE fp32->bf16
  union { float f; unsigned u; } c;
  c.f = x;
  unsigned r = c.u + 0x7FFFu + ((c.u >> 16) & 1u);
  return (unsigned short)(r >> 16);
}
__device__ inline float bf2f(unsigned short h) {
  union { float f; unsigned u; } c;
  c.u = (unsigned)h << 16;
  return c.f;
}

// Pre-pass: K -> {Khi, Klo} bf16 at [b][r][d ^ ((r&7)<<3)] (LDS-image order).
__global__ __launch_bounds__(256) void prep_k(const float* __restrict__ kp,
                                              unsigned short* __restrict__ khi,
                                              unsigned short* __restrict__ klo) {
  int idx = blockIdx.x * 256 + threadIdx.x;  // 524288 total
  int b = idx >> 15;
  int rem = idx & 32767;
  int r = rem >> 4;
  int d0 = (rem & 15) * 4;
  float4 kf = *(const float4*)(kp + ((size_t)b * LK + r) * DIM + d0);
  u16x4 hv, lv;
#pragma unroll
  for (int j = 0; j < 4; ++j) {
    float x = (&kf.x)[j];
    unsigned short hh = f2bf(x);
    hv[j] = hh;
    lv[j] = f2bf(x - bf2f(hh));
  }
  size_t ob = ((size_t)b * LK + r) * DIM + (d0 ^ ((r & 7) << 3));
  *(u16x4*)(khi + ob) = hv;
  *(u16x4*)(klo + ob) = lv;
}

// Pre-pass: V -> bf16 transposed per 64-tile: [b][tile][d][kin ^ ((d&7)<<3)].
__global__ __launch_bounds__(256) void prep_v(const float* __restrict__ vp,
                                              unsigned short* __restrict__ vt) {
  int idx = blockIdx.x * 256 + threadIdx.x;  // 131072 total
  int b = idx >> 13;
  int rem = idx & 8191;
  int kq = rem >> 4;  // 0..511
  int dq = rem & 15;
  int k0 = kq * 4;
  int tile = k0 >> 6;
  int kin = k0 & 63;
  const float* vg = vp + ((size_t)b * LK + k0) * DIM + dq * 4;
  unsigned short tmp[4][4];
#pragma unroll
  for (int j = 0; j < 4; ++j) {
    float4 vf = *(const float4*)(vg + j * DIM);
#pragma unroll
    for (int i2 = 0; i2 < 4; ++i2) tmp[j][i2] = f2bf((&vf.x)[i2]);
  }
  unsigned short* ob = vt + ((size_t)b * 32 + tile) * 4096;
#pragma unroll
  for (int j2 = 0; j2 < 4; ++j2) {
    u16x4 od = {tmp[0][j2], tmp[1][j2], tmp[2][j2], tmp[3][j2]};
    int d = dq * 4 + j2;
    *(u16x4*)(ob + d * 64 + (kin ^ ((d & 7) << 3))) = od;
  }
}

// mfma_f32_16x16x32_bf16: A row m=l&15 k=(l>>4)*8+e; B col n=l&15 same k;
// C/D col n=l&15, row m=(l>>4)*4+reg.
// launch_bounds 2nd arg == min BLOCKS/CU (R4 evidence). (512,2) -> 128-VGPR cap.
__global__ __launch_bounds__(BLOCK, 2) void attn_mfma(
    const float* __restrict__ qp, const unsigned short* __restrict__ khi_g,
    const unsigned short* __restrict__ klo_g,
    const unsigned short* __restrict__ vt_g,
    const uint32_t* __restrict__ maskp, const int* __restrict__ flagp,
    float* __restrict__ out) {
  __shared__ __align__(16) unsigned short arena[ARENA];

  const int tid = threadIdx.x;
  const int w = tid >> 6;
  const int l = tid & 63;
  const int lr = l & 15;
  const int lh = l >> 4;
  const int rg = w & 3;   // row-group
  const int h = w >> 2;   // k-half
  const int wl = w & 3;   // wave index within half
  const int t256 = tid & 255;
  // XCD-aware bijective swizzle (512 blocks, 8 XCDs)
  const int bid = (blockIdx.x & 7) * 64 + (blockIdx.x >> 3);
  const int b = bid >> 5;
  const int qt = bid & 31;
  const int qbase = qt * QB;
  const int isU8 = *flagp;

  unsigned short* Khi = arena + O_KHI + h * 4096;
  unsigned short* Klo = arena + O_KLO + h * 4096;
  unsigned short* Vt = arena + O_VT + h * 4096;
  unsigned short* Mnb = arena + O_MN + h * 256;
  unsigned short* Pw = arena + O_PL + w * 1024;

  // ---- Q fragments (hi/lo split) ----
  bf16x8 qh[2], ql[2];
  {
    const float* qr = qp + ((size_t)b * LQ + qbase + rg * 16 + lr) * DIM;
#pragma unroll
    for (int s = 0; s < 2; ++s) {
#pragma unroll
      for (int j2 = 0; j2 < 2; ++j2) {
        float4 x = *(const float4*)(qr + s * 32 + lh * 8 + j2 * 4);
#pragma unroll
        for (int j = 0; j < 4; ++j) {
          float xv = (&x.x)[j];
          unsigned short hh = f2bf(xv);
          qh[s][j2 * 4 + j] = (short)hh;
          ql[s][j2 * 4 + j] = (short)f2bf(xv - bf2f(hh));
        }
      }
    }
  }

  const int mrow = t256 >> 2;  // mask row (0..63)
  const int mc = t256 & 3;     // 16-col chunk within row

  uint4 pm4[4];
  const uint8_t* m8 = (const uint8_t*)maskp;
  auto loadM = [&](int kb) {
    if (!isU8) {
      const uint32_t* mg =
          maskp + ((size_t)b * LQ + qbase + mrow) * LK + kb + mc * 16;
#pragma unroll
      for (int i = 0; i < 4; ++i) pm4[i] = *(const uint4*)(mg + i * 4);
    } else {
      pm4[0] = *(const uint4*)(m8 + ((size_t)b * LQ + qbase + mrow) * LK + kb +
                               mc * 16);
    }
  };
  loadM(h * 1024);  // prologue prefetch t=0

  f32x4 acc_o[4];
#pragma unroll
  for (int g = 0; g < 4; ++g) acc_o[g] = (f32x4){0.f, 0.f, 0.f, 0.f};
  float den[4] = {0.f, 0.f, 0.f, 0.f};

  for (int t = 0; t < NT; ++t) {
    const int kb = h * 1024 + t * 64;
    bar_lds();  // prev tile's LDS consumers done
    // ---- mask bits from regs (tile t) ----
    {
      unsigned mv = 0;
      if (!isU8) {
#pragma unroll
        for (int i = 0; i < 4; ++i) {
          uint4 x = pm4[i];
          unsigned nib = (x.x != 0) | ((x.y != 0) << 1) | ((x.z != 0) << 2) |
                         ((x.w != 0) << 3);
          mv |= nib << (4 * i);
        }
      } else {
#pragma unroll
        for (int tt = 0; tt < 4; ++tt) {
          unsigned wv = (&pm4[0].x)[tt];
#pragma unroll
          for (int j = 0; j < 4; ++j)
            mv |= ((((wv >> (8 * j)) & 0xFFu) != 0u) ? 1u : 0u) << (4 * tt + j);
        }
      }
      Mnb[mrow * 4 + mc] = (unsigned short)mv;
    }
    // ---- stage this tile's Khi/Klo/Vt via global_load_lds (zero VALU) ----
    {
      const size_t tb = ((size_t)b * LK + kb) * 64;  // halfword offset
      const unsigned short* gk = khi_g + tb;
      const unsigned short* gq = klo_g + tb;
      const unsigned short* gv = vt_g + ((size_t)b * 32 + (kb >> 6)) * 4096;
#pragma unroll
      for (int c2 = 0; c2 < 2; ++c2) {
        const int c = wl * 2 + c2;
        const int off = c * 512 + l * 8;
        gl_lds16(gk + off, &Khi[c * 512]);
        gl_lds16(gq + off, &Klo[c * 512]);
        gl_lds16(gv + off, &Vt[c * 512]);
      }
    }
    __builtin_amdgcn_sched_barrier(0);
    // ---- issue next tile's mask loads; counted wait keeps them in flight ----
    if (t < NT - 1) {
      loadM(kb + 64);
      __builtin_amdgcn_sched_barrier(0);
      if (!isU8)
        asm volatile("s_waitcnt vmcnt(4) lgkmcnt(0)\n\ts_barrier" ::: "memory");
      else
        asm volatile("s_waitcnt vmcnt(1) lgkmcnt(0)\n\ts_barrier" ::: "memory");
    } else {
      asm volatile("s_waitcnt vmcnt(0) lgkmcnt(0)\n\ts_barrier" ::: "memory");
    }

    // ---- QK^T: S = Qhi*Khi + Qlo*Khi + Qhi*Klo ----
    f32x4 acc_s[4];
#pragma unroll
    for (int f = 0; f < 4; ++f) acc_s[f] = (f32x4){0.f, 0.f, 0.f, 0.f};
    __builtin_amdgcn_s_setprio(1);
#pragma unroll
    for (int f = 0; f < 4; ++f) {
      const int krow = f * 16 + lr;
#pragma unroll
      for (int s = 0; s < 2; ++s) {
        int csw = (s * 32 + lh * 8) ^ ((krow & 7) << 3);
        bf16x8 kh = *(const bf16x8*)&Khi[krow * 64 + csw];
        bf16x8 kl = *(const bf16x8*)&Klo[krow * 64 + csw];
        acc_s[f] = __builtin_amdgcn_mfma_f32_16x16x32_bf16(qh[s], kh, acc_s[f],
                                                           0, 0, 0);
        acc_s[f] = __builtin_amdgcn_mfma_f32_16x16x32_bf16(ql[s], kh, acc_s[f],
                                                           0, 0, 0);
        acc_s[f] = __builtin_amdgcn_mfma_f32_16x16x32_bf16(qh[s], kl, acc_s[f],
                                                           0, 0, 0);
      }
    }
    __builtin_amdgcn_s_setprio(0);

    // ---- mask + exp + P(bf16) ----
    unsigned long long mrows[4];
#pragma unroll
    for (int r = 0; r < 4; ++r)
      mrows[r] = *(const unsigned long long*)&Mnb[(rg * 16 + lh * 4 + r) * 4];
#pragma unroll
    for (int f = 0; f < 4; ++f) {
#pragma unroll
      for (int r = 0; r < 4; ++r) {
        int kc = f * 16 + lr;
        float e =
            ((mrows[r] >> kc) & 1ull) ? 1.0f : __expf(acc_s[f][r] * SCALE);
        den[r] += e;
        int qrow = lh * 4 + r;
        Pw[qrow * 64 + (kc ^ ((qrow & 7) << 3))] = f2bf(e);
      }
    }

    // ---- PV ----
#pragma unroll
    for (int s2 = 0; s2 < 2; ++s2) {
      bf16x8 pa =
          *(const bf16x8*)&Pw[lr * 64 + ((s2 * 32 + lh * 8) ^ ((lr & 7) << 3))];
      bf16x8 vbf[4];
#pragma unroll
      for (int g = 0; g < 4; ++g) {
        int d = g * 16 + lr;
        vbf[g] =
            *(const bf16x8*)&Vt[d * 64 + ((s2 * 32 + lh * 8) ^ ((d & 7) << 3))];
      }
      __builtin_amdgcn_s_setprio(1);
#pragma unroll
      for (int g = 0; g < 4; ++g) {
        acc_o[g] = __builtin_amdgcn_mfma_f32_16x16x32_bf16(pa, vbf[g], acc_o[g],
                                                           0, 0, 0);
      }
      __builtin_amdgcn_s_setprio(0);
      __builtin_amdgcn_sched_barrier(0);
    }
  }

  // ---- cross-half combine (waves w and w+4 share rows) ----
  __syncthreads();
  float* X = (float*)arena;  // stride 24 f32 -> 16B aligned per lane
  if (h == 1) {
    float* xp = X + ((size_t)((w - 4) * 64 + l)) * 24;
#pragma unroll
    for (int g = 0; g < 4; ++g) *(f32x4*)(xp + 4 * g) = acc_o[g];
#pragma unroll
    for (int r = 0; r < 4; ++r) xp[16 + r] = den[r];
  }
  __syncthreads();
  if (h == 0) {
    float* xp = X + ((size_t)(w * 64 + l)) * 24;
#pragma unroll
    for (int g = 0; g < 4; ++g) {
      f32x4 o2 = *(const f32x4*)(xp + 4 * g);
      acc_o[g] += o2;
    }
#pragma unroll
    for (int r = 0; r < 4; ++r) den[r] += xp[16 + r];
#pragma unroll
    for (int r = 0; r < 4; ++r) {
      den[r] += __shfl_xor(den[r], 1);
      den[r] += __shfl_xor(den[r], 2);
      den[r] += __shfl_xor(den[r], 4);
      den[r] += __shfl_xor(den[r], 8);
      den[r] = 1.0f / den[r];
    }
    float* ob = out + ((size_t)b * LQ + qbase + rg * 16) * DIM;
#pragma unroll
    for (int g = 0; g < 4; ++g) {
#pragma unroll
      for (int r = 0; r < 4; ++r) {
        ob[(lh * 4 + r) * DIM + g * 16 + lr] = acc_o[g][r] * den[r];
      }
    }
  }
}

}  // namespace

extern "C" void kernel_launch(void* const* d_in, const int* in_sizes, int n_in,
                              void* d_out, int out_size, void* d_ws,
                              size_t ws_size, hipStream_t stream) {
  const float* q = (const float*)d_in[0];
  const float* k = (const float*)d_in[1];
  const float* v = (const float*)d_in[2];
  const uint32_t* mask = (const uint32_t*)d_in[3];
  float* out = (float*)d_out;
  int* flag = (int*)d_ws;
  unsigned short* khi_g = (unsigned short*)((char*)d_ws + WS_KHI);
  unsigned short* klo_g = (unsigned short*)((char*)d_ws + WS_KLO);
  unsigned short* vt_g = (unsigned short*)((char*)d_ws + WS_VT);

  detect_mask_dtype<<<1, 256, 0, stream>>>(mask, flag);
  prep_k<<<2048, 256, 0, stream>>>(k, khi_g, klo_g);
  prep_v<<<512, 256, 0, stream>>>(v, vt_g);
  attn_mfma<<<dim3(BATCH * (LQ / QB)), BLOCK, 0, stream>>>(
      q, khi_g, klo_g, vt_g, mask, flag, out);
}